// Round 2
// baseline (475.595 us; speedup 1.0000x reference)
//
#include <hip/hip_runtime.h>

#define NNODE 100
#define HDIM  128
#define NEDGE 360
#define NT    512

typedef float f32x4 __attribute__((ext_vector_type(4)));
typedef short s16x8 __attribute__((ext_vector_type(8)));

__device__ __forceinline__ float bf2f(short s) {
  union { unsigned int u; float f; } v;
  v.u = ((unsigned int)(unsigned short)s) << 16;
  return v.f;
}
__device__ __forceinline__ short f2bf(float f) {  // RNE
  union { float f; unsigned int u; } v; v.f = f;
  unsigned int u = v.u + 0x7fffu + ((v.u >> 16) & 1u);
  return (short)(u >> 16);
}
// XOR-swizzled LDS index (shorts). Row stride 128 shorts (256B); 16B groups
// permuted by row&15 so stride-256B row accesses spread across all banks.
__device__ __forceinline__ int sidx(int r, int k) {
  return (r << 7) + ((((k >> 3) ^ (r & 15)) << 3) | (k & 7));
}
// fp32 h-buffer index: row stride 128 floats; columns XOR'd by row-bit so the
// 4-quad scalar stores land 2-way (free) instead of 4-way on banks.
__device__ __forceinline__ int hidx(int r, int c) {
  return (r << 7) + (c ^ ((r & 4) << 2));
}

// ---------------- prep 1: weight transposes (bf16 [n][k]) + incoming-edge lists ----
// wt slots (16384 shorts each): 0=W1, 1=Wc(=W2@Wu1b, filled by prep_fold),
//                               2=Wu1a, 3=Wu2
__global__ __launch_bounds__(NT)
void prep_tr(const float* __restrict__ w_msg1, const float* __restrict__ w_upd1,
             const float* __restrict__ w_upd2, const int* __restrict__ dst_idx,
             short* __restrict__ wt, int* __restrict__ inl) {
  int idx = blockIdx.x * NT + threadIdx.x;
  if (idx < 3 * 16384) {
    int m = idx >> 14, i = idx & 16383;
    int n = i >> 7, k = i & 127;
    const float* W = (m == 0) ? w_msg1 : (m == 1) ? w_upd1 : w_upd2;
    int slot = (m == 0) ? 0 : (m == 1) ? 2 : 3;
    wt[slot * 16384 + n * HDIM + k] = f2bf(W[k * HDIM + n]);
  }
  if (blockIdx.x == 0) {
    __shared__ int cnt[NNODE];
    int tid = threadIdx.x;
    if (tid < NNODE) cnt[tid] = 0;
    __syncthreads();
    if (tid < NEDGE) {
      int d = dst_idx[tid];
      int p = atomicAdd(&cnt[d], 1);
      inl[d * 4 + p] = tid;
    }
    __syncthreads();
    if (tid < NNODE) {
      for (int p = cnt[tid]; p < 4; ++p) inl[tid * 4 + p] = -1;
    }
  }
}

// ---------------- prep 2: fold GEMM2 into upd1.  Wc = W2 @ Wu1b,  bv = b2 @ Wu1b
__global__ __launch_bounds__(128)
void prep_fold(const float* __restrict__ w_msg2, const float* __restrict__ w_upd1,
               const float* __restrict__ b_msg2,
               short* __restrict__ wt, float* __restrict__ bv) {
  const int j = threadIdx.x;
  if (blockIdx.x < 128) {
    const int i = blockIdx.x;
    float s = 0.f;
#pragma unroll 4
    for (int k = 0; k < 128; ++k)
      s += w_msg2[i * HDIM + k] * w_upd1[(HDIM + k) * HDIM + j];
    wt[16384 + j * HDIM + i] = f2bf(s);   // B-layout: [n=j][k=i]
  } else {
    float s = 0.f;
#pragma unroll 4
    for (int k = 0; k < 128; ++k)
      s += b_msg2[k] * w_upd1[(HDIM + k) * HDIM + j];
    bv[j] = s;
  }
}

// ---------------- main fused kernel: one block per batch element, 61.6 KB LDS ----
// x never staged to LDS: A-fragments go global->regs once (reused P1+B1);
// residual x prefetched into regs at end of B1; h staged to LDS fp32 and
// stored with LN applied as coalesced float4.
__global__ __launch_bounds__(NT, 4)
void mpnn_main(const float* __restrict__ x,
               const int* __restrict__ src_idx,
               const float* __restrict__ edge_dir,
               const float* __restrict__ w_msg1,   // row 128 = edge-feature column
               const float* __restrict__ b_msg1,
               const float* __restrict__ b_upd1,
               const float* __restrict__ b_upd2,
               const float* __restrict__ gamma,
               const float* __restrict__ beta,
               const short* __restrict__ wt,
               const float* __restrict__ bv_g,
               const int* __restrict__ inl_g,
               float* __restrict__ out)
{
  __shared__ __align__(16) char smem[61568];
  short* bufT = (short*)smem;             // 25600 B: t, then u1
  short* bufM = (short*)(smem + 25600);   // 25600 B: magg
  float* hbuf = (float*)smem;             // 51200 B fp32 (epilogue reuse of T+M)
  float* lnb  = (float*)(smem + 51200);   // 1600 B: per-(row,wc) {s1,s2}
  int*   srcl = (int*)(smem + 52800);     // 1536
  float* eds  = (float*)(smem + 54336);   // 1536
  int*   inls = (int*)(smem + 55872);     // 1600
  float* cntf = (float*)(smem + 57472);   // 512 (rows 100..127 = 0)
  float* b1s  = (float*)(smem + 57984);
  float* w1ls = (float*)(smem + 58496);
  float* bvs  = (float*)(smem + 59008);
  float* bu1s = (float*)(smem + 59520);
  float* bu2s = (float*)(smem + 60032);
  float* gms  = (float*)(smem + 60544);
  float* bts  = (float*)(smem + 61056);

  const int tid  = threadIdx.x;
  const int lane = tid & 63;
  const int wave = tid >> 6;
  const int quad = lane >> 4;
  const int l16  = lane & 15;
  const int wr   = wave >> 1;   // 0..3  row group (32 rows)
  const int wc   = wave & 1;    // 0..1  col half (64 cols)
  const int b    = blockIdx.x;
  const float* xb = x + (size_t)b * (NNODE * HDIM);

  const int r0 = wr * 32 + l16;
  const int r1 = r0 + 16;
  const int m0 = (r0 < NNODE) ? r0 : 0;   // clamp garbage rows (outputs discarded)
  const int m1 = (r1 < NNODE) ? r1 : 0;

  s16x8 wf[4][4];   // B-fragments [ct][kq]
  auto loadB = [&](const short* w) {
#pragma unroll
    for (int ct = 0; ct < 4; ++ct)
#pragma unroll
      for (int kq = 0; kq < 4; ++kq)
        wf[ct][kq] = *(const s16x8*)&w[(wc * 64 + ct * 16 + l16) * HDIM + kq * 32 + quad * 8];
  };

  // ---- staging: W1 frags + x A-fragments straight to registers ----
  loadB(wt);   // W1
  s16x8 xa[2][4];   // retained x fragments [rt][kq] — reused in P1 AND B1
#pragma unroll
  for (int kq = 0; kq < 4; ++kq) {
    const int ko = kq * 32 + quad * 8;
#pragma unroll
    for (int rt = 0; rt < 2; ++rt) {
      const int rr = rt ? m1 : m0;
      const float4* p = (const float4*)(xb + rr * HDIM + ko);
      float4 v0 = p[0], v1 = p[1];
      s16x8 a;
      a[0] = f2bf(v0.x); a[1] = f2bf(v0.y); a[2] = f2bf(v0.z); a[3] = f2bf(v0.w);
      a[4] = f2bf(v1.x); a[5] = f2bf(v1.y); a[6] = f2bf(v1.z); a[7] = f2bf(v1.w);
      xa[rt][kq] = a;
    }
  }
  if (tid < 384) {
    srcl[tid] = (tid < NEDGE) ? src_idx[tid] : 0;
    eds[tid]  = (tid < NEDGE) ? edge_dir[tid] : 0.f;
  }
  if (tid < NNODE) {
    int4 il = ((const int4*)inl_g)[tid];
    ((int4*)inls)[tid] = il;
    cntf[tid] = (float)((il.x >= 0) + (il.y >= 0) + (il.z >= 0) + (il.w >= 0));
  } else if (tid < HDIM) {
    cntf[tid] = 0.f;
  }
  if (tid < HDIM) {
    b1s[tid]  = b_msg1[tid];
    w1ls[tid] = w_msg1[HDIM * HDIM + tid];
    bvs[tid]  = bv_g[tid];
    bu1s[tid] = b_upd1[tid];
    bu2s[tid] = b_upd2[tid];
    gms[tid]  = gamma[tid];
    bts[tid]  = beta[tid];
  }

  f32x4 xr[2][4];   // residual x (C-layout), filled at end of B1

  // ---- P1: t = x @ W1 -> bufT (no barrier needed before: all inputs in regs) ----
  {
    f32x4 acc[2][4] = {};
#pragma unroll
    for (int kq = 0; kq < 4; ++kq)
#pragma unroll
      for (int ct = 0; ct < 4; ++ct) {
        acc[0][ct] = __builtin_amdgcn_mfma_f32_16x16x32_bf16(xa[0][kq], wf[ct][kq], acc[0][ct], 0, 0, 0);
        acc[1][ct] = __builtin_amdgcn_mfma_f32_16x16x32_bf16(xa[1][kq], wf[ct][kq], acc[1][ct], 0, 0, 0);
      }
    loadB(wt + 16384);   // Wc; latency hides over epilogue+barrier+P2
#pragma unroll
    for (int rt = 0; rt < 2; ++rt)
#pragma unroll
      for (int i = 0; i < 4; ++i) {
        const int row = wr * 32 + rt * 16 + quad * 4 + i;
        if (row < NNODE) {
#pragma unroll
          for (int ct = 0; ct < 4; ++ct) {
            const int col = wc * 64 + ct * 16 + l16;
            bufT[sidx(row, col)] = f2bf(acc[rt][ct][i]);
          }
        }
      }
  }
  __syncthreads();

  // ---- P2: magg[v] = sum_{e into v} relu(t[src[e]] + b1 + ed[e]*w1L) -> bufM ----
  for (int G = tid; G < NNODE * 16; G += NT) {
    const int v = G >> 4, ko = (G & 15) * 8;
    const int4 il = ((const int4*)inls)[v];
    const float4 ba = *(const float4*)&b1s[ko];
    const float4 bb = *(const float4*)&b1s[ko + 4];
    const float4 wa = *(const float4*)&w1ls[ko];
    const float4 wb = *(const float4*)&w1ls[ko + 4];
    float s[8] = {0, 0, 0, 0, 0, 0, 0, 0};
    const int es[4] = {il.x, il.y, il.z, il.w};
#pragma unroll
    for (int j = 0; j < 4; ++j) {
      if (es[j] >= 0) {
        const int e = es[j];
        const float ed = eds[e];
        s16x8 t8 = *(const s16x8*)&bufT[sidx(srcl[e], ko)];
        float u;
        u = bf2f(t8[0]) + ba.x + ed * wa.x; s[0] += u > 0.f ? u : 0.f;
        u = bf2f(t8[1]) + ba.y + ed * wa.y; s[1] += u > 0.f ? u : 0.f;
        u = bf2f(t8[2]) + ba.z + ed * wa.z; s[2] += u > 0.f ? u : 0.f;
        u = bf2f(t8[3]) + ba.w + ed * wa.w; s[3] += u > 0.f ? u : 0.f;
        u = bf2f(t8[4]) + bb.x + ed * wb.x; s[4] += u > 0.f ? u : 0.f;
        u = bf2f(t8[5]) + bb.y + ed * wb.y; s[5] += u > 0.f ? u : 0.f;
        u = bf2f(t8[6]) + bb.z + ed * wb.z; s[6] += u > 0.f ? u : 0.f;
        u = bf2f(t8[7]) + bb.w + ed * wb.w; s[7] += u > 0.f ? u : 0.f;
      }
    }
    s16x8 o;
#pragma unroll
    for (int t = 0; t < 8; ++t) o[t] = f2bf(s[t]);
    *(s16x8*)&bufM[sidx(v, ko)] = o;
  }
  __syncthreads();

  // ---- B1: u1 = relu(magg @ Wc + x @ Wu1a + bu1 + cnt*bv) -> bufT ----
  {
    f32x4 acc[2][4] = {};
#pragma unroll
    for (int kq = 0; kq < 4; ++kq) {
      const int ko = kq * 32 + quad * 8;
      s16x8 a0 = *(const s16x8*)&bufM[sidx(m0, ko)];
      s16x8 a1 = *(const s16x8*)&bufM[sidx(m1, ko)];
#pragma unroll
      for (int ct = 0; ct < 4; ++ct) {
        acc[0][ct] = __builtin_amdgcn_mfma_f32_16x16x32_bf16(a0, wf[ct][kq], acc[0][ct], 0, 0, 0);
        acc[1][ct] = __builtin_amdgcn_mfma_f32_16x16x32_bf16(a1, wf[ct][kq], acc[1][ct], 0, 0, 0);
      }
    }
    loadB(wt + 2 * 16384);   // Wu1a
    // x-half from retained registers — no global re-read
#pragma unroll
    for (int kq = 0; kq < 4; ++kq)
#pragma unroll
      for (int ct = 0; ct < 4; ++ct) {
        acc[0][ct] = __builtin_amdgcn_mfma_f32_16x16x32_bf16(xa[0][kq], wf[ct][kq], acc[0][ct], 0, 0, 0);
        acc[1][ct] = __builtin_amdgcn_mfma_f32_16x16x32_bf16(xa[1][kq], wf[ct][kq], acc[1][ct], 0, 0, 0);
      }
    loadB(wt + 3 * 16384);   // Wu2; latency overlaps epilogue+barrier
    // residual prefetch (C-layout; 64B-coalesced) — used in B2 epilogue,
    // a barrier + full MFMA phase later. xa dies here, xr is born: neutral VGPR peak.
#pragma unroll
    for (int rt = 0; rt < 2; ++rt)
#pragma unroll
      for (int i = 0; i < 4; ++i) {
        const int row = wr * 32 + rt * 16 + quad * 4 + i;
        const int rr = (row < NNODE) ? row : 0;
#pragma unroll
        for (int ct = 0; ct < 4; ++ct) {
          const int col = wc * 64 + ct * 16 + l16;
          xr[rt][ct][i] = xb[rr * HDIM + col];
        }
      }
#pragma unroll
    for (int rt = 0; rt < 2; ++rt)
#pragma unroll
      for (int i = 0; i < 4; ++i) {
        const int row = wr * 32 + rt * 16 + quad * 4 + i;
        if (row < NNODE) {
          const float cn = cntf[row];
#pragma unroll
          for (int ct = 0; ct < 4; ++ct) {
            const int col = wc * 64 + ct * 16 + l16;
            float v = acc[rt][ct][i] + bu1s[col] + cn * bvs[col];
            bufT[sidx(row, col)] = f2bf(v > 0.f ? v : 0.f);
          }
        }
      }
  }
  __syncthreads();

  // ---- B2: h = u1 @ Wu2 + bu2 + x; LN stats; h -> hbuf; coalesced LN store ----
  {
    f32x4 acc[2][4] = {};
#pragma unroll
    for (int kq = 0; kq < 4; ++kq) {
      const int ko = kq * 32 + quad * 8;
      s16x8 a0 = *(const s16x8*)&bufT[sidx(m0, ko)];
      s16x8 a1 = *(const s16x8*)&bufT[sidx(m1, ko)];
#pragma unroll
      for (int ct = 0; ct < 4; ++ct) {
        acc[0][ct] = __builtin_amdgcn_mfma_f32_16x16x32_bf16(a0, wf[ct][kq], acc[0][ct], 0, 0, 0);
        acc[1][ct] = __builtin_amdgcn_mfma_f32_16x16x32_bf16(a1, wf[ct][kq], acc[1][ct], 0, 0, 0);
      }
    }
    __syncthreads();   // all u1 reads done before hbuf overwrites bufT/bufM
#pragma unroll
    for (int rt = 0; rt < 2; ++rt)
#pragma unroll
      for (int i = 0; i < 4; ++i) {
        const int row = wr * 32 + rt * 16 + quad * 4 + i;
        if (row < NNODE) {
          float s1 = 0.f, s2 = 0.f;
#pragma unroll
          for (int ct = 0; ct < 4; ++ct) {
            const int col = wc * 64 + ct * 16 + l16;
            const float h = acc[rt][ct][i] + bu2s[col] + xr[rt][ct][i];
            hbuf[hidx(row, col)] = h;
            s1 += h; s2 += h * h;
          }
          // reduce this row's 64-col partials across the 16 lanes holding it
#pragma unroll
          for (int off = 8; off > 0; off >>= 1) {
            s1 += __shfl_xor(s1, off, 64);
            s2 += __shfl_xor(s2, off, 64);
          }
          if (l16 == 0) { lnb[row * 4 + wc * 2] = s1; lnb[row * 4 + wc * 2 + 1] = s2; }
        }
      }
    __syncthreads();
    // final: LN-apply + fully coalesced float4 stores
    for (int G = tid; G < NNODE * 32; G += NT) {
      const int row = G >> 5;
      const int c = (G & 31) * 4;
      const float4 h = *(const float4*)&hbuf[hidx(row, c)];
      const float s1 = lnb[row * 4] + lnb[row * 4 + 2];
      const float s2 = lnb[row * 4 + 1] + lnb[row * 4 + 3];
      const float mu  = s1 * (1.0f / HDIM);
      const float var = s2 * (1.0f / HDIM) - mu * mu;
      const float rs  = rsqrtf(var + 1e-5f);
      const float4 g  = *(const float4*)&gms[c];
      const float4 bt = *(const float4*)&bts[c];
      float4 o;
      o.x = (h.x - mu) * rs * g.x + bt.x;
      o.y = (h.y - mu) * rs * g.y + bt.y;
      o.z = (h.z - mu) * rs * g.z + bt.z;
      o.w = (h.w - mu) * rs * g.w + bt.w;
      *(float4*)&out[((size_t)b * NNODE + row) * HDIM + c] = o;
    }
  }
}

extern "C" void kernel_launch(void* const* d_in, const int* in_sizes, int n_in,
                              void* d_out, int out_size, void* d_ws, size_t ws_size,
                              hipStream_t stream) {
  const float* x      = (const float*)d_in[0];
  const int*   src    = (const int*)  d_in[1];
  const int*   dst    = (const int*)  d_in[2];
  const float* ed     = (const float*)d_in[3];
  const float* w_msg1 = (const float*)d_in[4];
  const float* b_msg1 = (const float*)d_in[5];
  const float* w_msg2 = (const float*)d_in[6];
  const float* b_msg2 = (const float*)d_in[7];
  const float* w_upd1 = (const float*)d_in[8];
  const float* b_upd1 = (const float*)d_in[9];
  const float* w_upd2 = (const float*)d_in[10];
  const float* b_upd2 = (const float*)d_in[11];
  const float* gamma  = (const float*)d_in[12];
  const float* beta   = (const float*)d_in[13];
  float* out = (float*)d_out;

  short* wt  = (short*)d_ws;                      // 4 * 32768 B (W1, Wc, Wu1a, Wu2)
  float* bv  = (float*)((char*)d_ws + 131072);    // 512 B
  int*   inl = (int*)((char*)d_ws + 131584);      // 100 * int4

  prep_tr<<<96, NT, 0, stream>>>(w_msg1, w_upd1, w_upd2, dst, wt, inl);
  prep_fold<<<129, 128, 0, stream>>>(w_msg2, w_upd1, b_msg2, wt, bv);

  const int Bsz = in_sizes[0] / (NNODE * HDIM);   // 2048
  mpnn_main<<<Bsz, NT, 0, stream>>>(x, src, ed, w_msg1, b_msg1,
                                    b_upd1, b_upd2, gamma, beta, wt, bv, inl, out);
}

// Round 3
// 386.203 us; speedup vs baseline: 1.2315x; 1.2315x over previous
//
#include <hip/hip_runtime.h>

#define NNODE 100
#define HDIM  128
#define NEDGE 360
#define NT    512

typedef float f32x4 __attribute__((ext_vector_type(4)));
typedef short s16x8 __attribute__((ext_vector_type(8)));

__device__ __forceinline__ float bf2f(short s) {
  union { unsigned int u; float f; } v;
  v.u = ((unsigned int)(unsigned short)s) << 16;
  return v.f;
}
__device__ __forceinline__ short f2bf(float f) {  // RNE
  union { float f; unsigned int u; } v; v.f = f;
  unsigned int u = v.u + 0x7fffu + ((v.u >> 16) & 1u);
  return (short)(u >> 16);
}
// XOR-swizzled LDS index (shorts). Row stride 128 shorts (256B); 16B groups
// permuted by row&15 so stride-256B row accesses spread across all banks.
__device__ __forceinline__ int sidx(int r, int k) {
  return (r << 7) + ((((k >> 3) ^ (r & 15)) << 3) | (k & 7));
}
// fp32 h-buffer index: row stride 128 floats; columns XOR'd by row-bit so the
// quad-pattern scalar stores land 2-way (free) instead of 4-way on banks.
__device__ __forceinline__ int hidx(int r, int c) {
  return (r << 7) + (c ^ ((r & 4) << 2));
}

// ---------------- merged prep: transposes + fold + edge lists, ONE launch ----
// wt slots (16384 shorts): 0=W1, 1=Wc(=W2@Wu1b), 2=Wu1a, 3=Wu2
// blocks 0..95: bf16 transposes of W1/Wu1a/Wu2 (block 0 also builds edge lists)
// blocks 96..128: Wc = W2 @ Wu1b (fp32), bv = b2 @ Wu1b
__global__ __launch_bounds__(NT)
void prep_all(const float* __restrict__ w_msg1, const float* __restrict__ w_msg2,
              const float* __restrict__ w_upd1, const float* __restrict__ w_upd2,
              const float* __restrict__ b_msg2, const int* __restrict__ dst_idx,
              short* __restrict__ wt, float* __restrict__ bv, int* __restrict__ inl) {
  __shared__ int cnt[NNODE];
  const int bid = blockIdx.x, tid = threadIdx.x;
  if (bid < 96) {
    const int idx = bid * NT + tid;          // < 49152
    const int m = idx >> 14, i = idx & 16383;
    const int n = i >> 7, k = i & 127;
    const float* W = (m == 0) ? w_msg1 : (m == 1) ? w_upd1 : w_upd2;
    const int slot = (m == 0) ? 0 : (m == 1) ? 2 : 3;
    wt[slot * 16384 + n * HDIM + k] = f2bf(W[k * HDIM + n]);
    if (bid == 0) {
      if (tid < NNODE) cnt[tid] = 0;
      __syncthreads();
      if (tid < NEDGE) {
        int d = dst_idx[tid];
        int p = atomicAdd(&cnt[d], 1);
        inl[d * 4 + p] = tid;
      }
      __syncthreads();
      if (tid < NNODE)
        for (int p = cnt[tid]; p < 4; ++p) inl[tid * 4 + p] = -1;
    }
  } else {
    const int u = (bid - 96) * NT + tid;     // < 16896
    const int i = u >> 7, j = u & 127;
    if (i < 128) {
      float s = 0.f;
#pragma unroll 4
      for (int k = 0; k < 128; ++k)
        s += w_msg2[i * HDIM + k] * w_upd1[(HDIM + k) * HDIM + j];
      wt[16384 + j * HDIM + i] = f2bf(s);    // B-layout: [n=j][k=i]
    } else if (i == 128) {
      float s = 0.f;
#pragma unroll 4
      for (int k = 0; k < 128; ++k)
        s += b_msg2[k] * w_upd1[(HDIM + k) * HDIM + j];
      bv[j] = s;
    }
  }
}

// ---------------- main fused kernel: one block per batch element, 81744 B LDS ----
// x staged ONCE to LDS bf16 (lives through B1); h staged to LDS fp32 and stored
// with LN as coalesced float4. No persistent per-thread arrays beyond wf+acc.
__global__ __launch_bounds__(NT, 4)
void mpnn_main(const float* __restrict__ x,
               const int* __restrict__ src_idx,
               const float* __restrict__ edge_dir,
               const float* __restrict__ w_msg1,   // row 128 = edge-feature column
               const float* __restrict__ b_msg1,
               const float* __restrict__ b_upd1,
               const float* __restrict__ b_upd2,
               const float* __restrict__ gamma,
               const float* __restrict__ beta,
               const short* __restrict__ wt,
               const float* __restrict__ bv_g,
               const int* __restrict__ inl_g,
               float* __restrict__ out)
{
  __shared__ __align__(16) char smem[81744];
  short* bufT = (short*)smem;                  // 25600: t, then u1
  short* bufX = (short*)(smem + 25600);        // 25600: x bf16 (stage..B1)
  short* bufM = (short*)(smem + 51200);        // 25600: magg (P2..B1)
  float* hbuf = (float*)(smem + 25600);        // 51200 fp32, overlays X+M in B2
  short* ep   = (short*)(smem + 76800);        // 768: packed src|dir<<7 (..P2)
  int*   inls = (int*)(smem + 77568);          // 1600 (..B1)
  float* lnb  = (float*)(smem + 76800);        // 1600 overlay of ep/inls (B2 only)
  float* edv  = (float*)(smem + 79168);        // 16: dir code -> exact fp32 dir
  float* bvs  = (float*)(smem + 79184);        // 512
  float* bu1s = (float*)(smem + 79696);        // 512
  float* bu2s = (float*)(smem + 80208);        // 512
  float* gms  = (float*)(smem + 80720);        // 512
  float* bts  = (float*)(smem + 81232);        // 512   -> total 81744 <= 81920

  const int tid  = threadIdx.x;
  const int lane = tid & 63;
  const int wave = tid >> 6;
  const int quad = lane >> 4;
  const int l16  = lane & 15;
  const int wr   = wave >> 1;   // 0..3  row group (32 rows)
  const int wc   = wave & 1;    // 0..1  col half (64 cols)
  const int b    = blockIdx.x;
  const float* xb = x + (size_t)b * (NNODE * HDIM);

  const int r0 = wr * 32 + l16;
  const int r1 = r0 + 16;
  const int m0 = (r0 < NNODE) ? r0 : 0;   // clamp garbage rows (outputs discarded)
  const int m1 = (r1 < NNODE) ? r1 : 0;

  s16x8 wf[4][4];   // B-fragments [ct][kq]
  auto loadB = [&](const short* w) {
#pragma unroll
    for (int ct = 0; ct < 4; ++ct)
#pragma unroll
      for (int kq = 0; kq < 4; ++kq)
        wf[ct][kq] = *(const s16x8*)&w[(wc * 64 + ct * 16 + l16) * HDIM + kq * 32 + quad * 8];
  };

  // ---- staging ----
  loadB(wt);   // W1; global latency overlaps LDS staging below
  for (int G = tid; G < NNODE * 16; G += NT) {
    int r = G >> 4, g = G & 15;
    const float4* p = (const float4*)(xb + r * HDIM + g * 8);
    float4 v0 = p[0], v1 = p[1];
    s16x8 h;
    h[0] = f2bf(v0.x); h[1] = f2bf(v0.y); h[2] = f2bf(v0.z); h[3] = f2bf(v0.w);
    h[4] = f2bf(v1.x); h[5] = f2bf(v1.y); h[6] = f2bf(v1.z); h[7] = f2bf(v1.w);
    *(s16x8*)&bufX[sidx(r, g * 8)] = h;
  }
  if (tid < 384) {
    int s = (tid < NEDGE) ? src_idx[tid] : 0;
    float e = (tid < NEDGE) ? edge_dir[tid] : 0.f;
    int d = (int)(e * 3.0f + 0.5f);            // dir code 0..3
    ep[tid] = (short)(s | (d << 7));
    if (tid < NEDGE) edv[d] = e;               // benign same-value race
  }
  if (tid < NNODE) ((int4*)inls)[tid] = ((const int4*)inl_g)[tid];
  if (tid < HDIM) {
    bvs[tid]  = bv_g[tid];
    bu1s[tid] = b_upd1[tid];
    bu2s[tid] = b_upd2[tid];
    gms[tid]  = gamma[tid];
    bts[tid]  = beta[tid];
  }
  __syncthreads();

  // ---- P1: t = x @ W1 -> bufT ----
  {
    f32x4 acc[2][4] = {};
#pragma unroll
    for (int kq = 0; kq < 4; ++kq) {
      const int ko = kq * 32 + quad * 8;
      s16x8 a0 = *(const s16x8*)&bufX[sidx(m0, ko)];
      s16x8 a1 = *(const s16x8*)&bufX[sidx(m1, ko)];
#pragma unroll
      for (int ct = 0; ct < 4; ++ct) {
        acc[0][ct] = __builtin_amdgcn_mfma_f32_16x16x32_bf16(a0, wf[ct][kq], acc[0][ct], 0, 0, 0);
        acc[1][ct] = __builtin_amdgcn_mfma_f32_16x16x32_bf16(a1, wf[ct][kq], acc[1][ct], 0, 0, 0);
      }
    }
    loadB(wt + 16384);   // Wc; latency hides over epilogue+barrier+P2
#pragma unroll
    for (int rt = 0; rt < 2; ++rt)
#pragma unroll
      for (int i = 0; i < 4; ++i) {
        const int row = wr * 32 + rt * 16 + quad * 4 + i;
        if (row < NNODE) {   // MUST guard: bufT is only 100 rows
#pragma unroll
          for (int ct = 0; ct < 4; ++ct) {
            const int col = wc * 64 + ct * 16 + l16;
            bufT[sidx(row, col)] = f2bf(acc[rt][ct][i]);
          }
        }
      }
  }
  __syncthreads();

  // ---- P2: magg[v] = sum_{e into v} relu(t[src[e]] + b1 + ed[e]*w1L) -> bufM ----
  {
    const int ko = (tid & 15) * 8;   // constant across this thread's iterations
    const float4 ba = *(const float4*)&b_msg1[ko];
    const float4 bb = *(const float4*)&b_msg1[ko + 4];
    const float4 wa = *(const float4*)&w_msg1[HDIM * HDIM + ko];
    const float4 wb = *(const float4*)&w_msg1[HDIM * HDIM + ko + 4];
    for (int G = tid; G < NNODE * 16; G += NT) {
      const int v = G >> 4;
      const int4 il = ((const int4*)inls)[v];
      float s[8] = {0, 0, 0, 0, 0, 0, 0, 0};
      const int es[4] = {il.x, il.y, il.z, il.w};
#pragma unroll
      for (int j = 0; j < 4; ++j) {
        if (es[j] >= 0) {
          const int pk = ep[es[j]];
          const float ed = edv[pk >> 7];
          s16x8 t8 = *(const s16x8*)&bufT[sidx(pk & 127, ko)];
          float u;
          u = bf2f(t8[0]) + ba.x + ed * wa.x; s[0] += u > 0.f ? u : 0.f;
          u = bf2f(t8[1]) + ba.y + ed * wa.y; s[1] += u > 0.f ? u : 0.f;
          u = bf2f(t8[2]) + ba.z + ed * wa.z; s[2] += u > 0.f ? u : 0.f;
          u = bf2f(t8[3]) + ba.w + ed * wa.w; s[3] += u > 0.f ? u : 0.f;
          u = bf2f(t8[4]) + bb.x + ed * wb.x; s[4] += u > 0.f ? u : 0.f;
          u = bf2f(t8[5]) + bb.y + ed * wb.y; s[5] += u > 0.f ? u : 0.f;
          u = bf2f(t8[6]) + bb.z + ed * wb.z; s[6] += u > 0.f ? u : 0.f;
          u = bf2f(t8[7]) + bb.w + ed * wb.w; s[7] += u > 0.f ? u : 0.f;
        }
      }
      s16x8 o;
#pragma unroll
      for (int t = 0; t < 8; ++t) o[t] = f2bf(s[t]);
      *(s16x8*)&bufM[sidx(v, ko)] = o;
    }
  }
  __syncthreads();

  // ---- B1: u1 = relu(magg @ Wc + x @ Wu1a + bu1 + cnt*bv) -> bufT ----
  {
    f32x4 acc[2][4] = {};
#pragma unroll
    for (int kq = 0; kq < 4; ++kq) {
      const int ko = kq * 32 + quad * 8;
      s16x8 a0 = *(const s16x8*)&bufM[sidx(m0, ko)];
      s16x8 a1 = *(const s16x8*)&bufM[sidx(m1, ko)];
#pragma unroll
      for (int ct = 0; ct < 4; ++ct) {
        acc[0][ct] = __builtin_amdgcn_mfma_f32_16x16x32_bf16(a0, wf[ct][kq], acc[0][ct], 0, 0, 0);
        acc[1][ct] = __builtin_amdgcn_mfma_f32_16x16x32_bf16(a1, wf[ct][kq], acc[1][ct], 0, 0, 0);
      }
    }
    loadB(wt + 2 * 16384);   // Wu1a
    // x-half from LDS (bufX still live) — no global re-read
#pragma unroll
    for (int kq = 0; kq < 4; ++kq) {
      const int ko = kq * 32 + quad * 8;
      s16x8 a0 = *(const s16x8*)&bufX[sidx(m0, ko)];
      s16x8 a1 = *(const s16x8*)&bufX[sidx(m1, ko)];
#pragma unroll
      for (int ct = 0; ct < 4; ++ct) {
        acc[0][ct] = __builtin_amdgcn_mfma_f32_16x16x32_bf16(a0, wf[ct][kq], acc[0][ct], 0, 0, 0);
        acc[1][ct] = __builtin_amdgcn_mfma_f32_16x16x32_bf16(a1, wf[ct][kq], acc[1][ct], 0, 0, 0);
      }
    }
    loadB(wt + 3 * 16384);   // Wu2; latency overlaps epilogue+barrier
#pragma unroll
    for (int rt = 0; rt < 2; ++rt)
#pragma unroll
      for (int i = 0; i < 4; ++i) {
        const int row = wr * 32 + rt * 16 + quad * 4 + i;
        if (row < NNODE) {
          const int4 il = ((const int4*)inls)[row];
          const float cn = (float)((il.x >= 0) + (il.y >= 0) + (il.z >= 0) + (il.w >= 0));
#pragma unroll
          for (int ct = 0; ct < 4; ++ct) {
            const int col = wc * 64 + ct * 16 + l16;
            float v = acc[rt][ct][i] + bu1s[col] + cn * bvs[col];
            bufT[sidx(row, col)] = f2bf(v > 0.f ? v : 0.f);
          }
        }
      }
  }
  __syncthreads();

  // ---- B2: h = u1 @ Wu2 + bu2 + x; LN stats; h -> hbuf; coalesced LN store ----
  {
    f32x4 acc[2][4] = {};
#pragma unroll
    for (int kq = 0; kq < 4; ++kq) {
      const int ko = kq * 32 + quad * 8;
      s16x8 a0 = *(const s16x8*)&bufT[sidx(m0, ko)];
      s16x8 a1 = *(const s16x8*)&bufT[sidx(m1, ko)];
#pragma unroll
      for (int ct = 0; ct < 4; ++ct) {
        acc[0][ct] = __builtin_amdgcn_mfma_f32_16x16x32_bf16(a0, wf[ct][kq], acc[0][ct], 0, 0, 0);
        acc[1][ct] = __builtin_amdgcn_mfma_f32_16x16x32_bf16(a1, wf[ct][kq], acc[1][ct], 0, 0, 0);
      }
    }
    // hbuf overlays bufX+bufM (dead since barrier 4); disjoint from bufT reads -> no
    // extra barrier needed before these writes.
#pragma unroll
    for (int rt = 0; rt < 2; ++rt)
#pragma unroll
      for (int i = 0; i < 4; ++i) {
        const int row = wr * 32 + rt * 16 + quad * 4 + i;
        if (row < NNODE) {
          float s1 = 0.f, s2 = 0.f;
#pragma unroll
          for (int ct = 0; ct < 4; ++ct) {
            const int col = wc * 64 + ct * 16 + l16;
            const float h = acc[rt][ct][i] + bu2s[col] + xb[row * HDIM + col];
            hbuf[hidx(row, col)] = h;
            s1 += h; s2 += h * h;
          }
          // reduce this row's 64-col partials across the 16 lanes holding it
#pragma unroll
          for (int off = 8; off > 0; off >>= 1) {
            s1 += __shfl_xor(s1, off, 64);
            s2 += __shfl_xor(s2, off, 64);
          }
          if (l16 == 0) { lnb[row * 4 + wc * 2] = s1; lnb[row * 4 + wc * 2 + 1] = s2; }
        }
      }
    __syncthreads();
    // final: LN-apply + fully coalesced float4 stores (512B contiguous per row)
    for (int G = tid; G < NNODE * 32; G += NT) {
      const int row = G >> 5;
      const int c = (G & 31) * 4;
      const float4 h = *(const float4*)&hbuf[hidx(row, c)];
      const float s1 = lnb[row * 4] + lnb[row * 4 + 2];
      const float s2 = lnb[row * 4 + 1] + lnb[row * 4 + 3];
      const float mu  = s1 * (1.0f / HDIM);
      const float var = s2 * (1.0f / HDIM) - mu * mu;
      const float rs  = rsqrtf(var + 1e-5f);
      const float4 g  = *(const float4*)&gms[c];
      const float4 bt = *(const float4*)&bts[c];
      float4 o;
      o.x = (h.x - mu) * rs * g.x + bt.x;
      o.y = (h.y - mu) * rs * g.y + bt.y;
      o.z = (h.z - mu) * rs * g.z + bt.z;
      o.w = (h.w - mu) * rs * g.w + bt.w;
      *(float4*)&out[((size_t)b * NNODE + row) * HDIM + c] = o;
    }
  }
}

extern "C" void kernel_launch(void* const* d_in, const int* in_sizes, int n_in,
                              void* d_out, int out_size, void* d_ws, size_t ws_size,
                              hipStream_t stream) {
  const float* x      = (const float*)d_in[0];
  const int*   src    = (const int*)  d_in[1];
  const int*   dst    = (const int*)  d_in[2];
  const float* ed     = (const float*)d_in[3];
  const float* w_msg1 = (const float*)d_in[4];
  const float* b_msg1 = (const float*)d_in[5];
  const float* w_msg2 = (const float*)d_in[6];
  const float* b_msg2 = (const float*)d_in[7];
  const float* w_upd1 = (const float*)d_in[8];
  const float* b_upd1 = (const float*)d_in[9];
  const float* w_upd2 = (const float*)d_in[10];
  const float* b_upd2 = (const float*)d_in[11];
  const float* gamma  = (const float*)d_in[12];
  const float* beta   = (const float*)d_in[13];
  float* out = (float*)d_out;

  short* wt  = (short*)d_ws;                      // 4 * 32768 B (W1, Wc, Wu1a, Wu2)
  float* bv  = (float*)((char*)d_ws + 131072);    // 512 B
  int*   inl = (int*)((char*)d_ws + 131584);      // 100 * int4

  prep_all<<<129, NT, 0, stream>>>(w_msg1, w_msg2, w_upd1, w_upd2, b_msg2,
                                   dst, wt, bv, inl);

  const int Bsz = in_sizes[0] / (NNODE * HDIM);   // 2048
  mpnn_main<<<Bsz, NT, 0, stream>>>(x, src, ed, w_msg1, b_msg1,
                                    b_upd1, b_upd2, gamma, beta, wt, bv, inl, out);
}

// Round 4
// 350.206 us; speedup vs baseline: 1.3580x; 1.1028x over previous
//
#include <hip/hip_runtime.h>

#define NNODE 100
#define HDIM  128
#define NEDGE 360
#define NT    512

typedef float f32x4 __attribute__((ext_vector_type(4)));
typedef short s16x8 __attribute__((ext_vector_type(8)));

__device__ __forceinline__ float bf2f(short s) {
  union { unsigned int u; float f; } v;
  v.u = ((unsigned int)(unsigned short)s) << 16;
  return v.f;
}
__device__ __forceinline__ short f2bf(float f) {  // RNE
  union { float f; unsigned int u; } v; v.f = f;
  unsigned int u = v.u + 0x7fffu + ((v.u >> 16) & 1u);
  return (short)(u >> 16);
}
// XOR-swizzled LDS index (shorts). Row stride 128 shorts (256B); 16B groups
// permuted by row&15 so stride-256B row accesses spread across all banks.
__device__ __forceinline__ int sidx(int r, int k) {
  return (r << 7) + ((((k >> 3) ^ (r & 15)) << 3) | (k & 7));
}
// fp32 h-buffer index: row stride 128 floats; columns XOR'd by row-bit so the
// quad-pattern scalar stores land 2-way (free) instead of 4-way on banks.
__device__ __forceinline__ int hidx(int r, int c) {
  return (r << 7) + (c ^ ((r & 4) << 2));
}

// ---------------- merged prep: transposes + fold + edge lists, ONE launch ----
// wt slots (16384 shorts): 0=W1, 1=Wc(=W2@Wu1b), 2=Wu1a, 3=Wu2
// blocks 0..95: bf16 transposes of W1/Wu1a/Wu2 (block 0 also builds edge lists)
// blocks 96..128: Wc = W2 @ Wu1b (fp32), bv = b2 @ Wu1b
__global__ __launch_bounds__(NT)
void prep_all(const float* __restrict__ w_msg1, const float* __restrict__ w_msg2,
              const float* __restrict__ w_upd1, const float* __restrict__ w_upd2,
              const float* __restrict__ b_msg2, const int* __restrict__ dst_idx,
              short* __restrict__ wt, float* __restrict__ bv, int* __restrict__ inl) {
  __shared__ int cnt[NNODE];
  const int bid = blockIdx.x, tid = threadIdx.x;
  if (bid < 96) {
    const int idx = bid * NT + tid;          // < 49152
    const int m = idx >> 14, i = idx & 16383;
    const int n = i >> 7, k = i & 127;
    const float* W = (m == 0) ? w_msg1 : (m == 1) ? w_upd1 : w_upd2;
    const int slot = (m == 0) ? 0 : (m == 1) ? 2 : 3;
    wt[slot * 16384 + n * HDIM + k] = f2bf(W[k * HDIM + n]);
    if (bid == 0) {
      if (tid < NNODE) cnt[tid] = 0;
      __syncthreads();
      if (tid < NEDGE) {
        int d = dst_idx[tid];
        int p = atomicAdd(&cnt[d], 1);
        inl[d * 4 + p] = tid;
      }
      __syncthreads();
      if (tid < NNODE)
        for (int p = cnt[tid]; p < 4; ++p) inl[tid * 4 + p] = -1;
    }
  } else {
    const int u = (bid - 96) * NT + tid;     // < 16896
    const int i = u >> 7, j = u & 127;
    if (i < 128) {
      float s = 0.f;
#pragma unroll 4
      for (int k = 0; k < 128; ++k)
        s += w_msg2[i * HDIM + k] * w_upd1[(HDIM + k) * HDIM + j];
      wt[16384 + j * HDIM + i] = f2bf(s);    // B-layout: [n=j][k=i]
    } else if (i == 128) {
      float s = 0.f;
#pragma unroll 4
      for (int k = 0; k < 128; ++k)
        s += b_msg2[k] * w_upd1[(HDIM + k) * HDIM + j];
      bv[j] = s;
    }
  }
}

// ---------------- main fused kernel: one block per batch element, 81744 B LDS ----
// B-fragments are loaded per-(kq,ct) from L2-hot wt inside each phase (ONE base
// address + immediate offsets) — no persistent wf[4][4], so the ~92-reg live set
// that spilled in rounds 0-3 drops to ~30 arch VGPRs. acc lives in the AGPR half.
__global__ __launch_bounds__(NT, 4)
void mpnn_main(const float* __restrict__ x,
               const int* __restrict__ src_idx,
               const float* __restrict__ edge_dir,
               const float* __restrict__ w_msg1,   // row 128 = edge-feature column
               const float* __restrict__ b_msg1,
               const float* __restrict__ b_upd1,
               const float* __restrict__ b_upd2,
               const float* __restrict__ gamma,
               const float* __restrict__ beta,
               const short* __restrict__ wt,
               const float* __restrict__ bv_g,
               const int* __restrict__ inl_g,
               float* __restrict__ out)
{
  __shared__ __align__(16) char smem[81744];
  short* bufT = (short*)smem;                  // 25600: t, then u1
  short* bufX = (short*)(smem + 25600);        // 25600: x bf16 (stage..B1)
  short* bufM = (short*)(smem + 51200);        // 25600: magg (P2..B1)
  float* hbuf = (float*)(smem + 25600);        // 51200 fp32, overlays X+M in B2
  short* ep   = (short*)(smem + 76800);        // 768: packed src|dir<<7 (..P2)
  int*   inls = (int*)(smem + 77568);          // 1600 (..B1)
  float* lnb  = (float*)(smem + 76800);        // 1600 overlay of ep/inls (B2 only)
  float* edv  = (float*)(smem + 79168);        // 16: dir code -> exact fp32 dir
  float* bvs  = (float*)(smem + 79184);        // 512
  float* bu1s = (float*)(smem + 79696);        // 512
  float* bu2s = (float*)(smem + 80208);        // 512
  float* gms  = (float*)(smem + 80720);        // 512
  float* bts  = (float*)(smem + 81232);        // 512   -> total 81744 <= 81920

  const int tid  = threadIdx.x;
  const int lane = tid & 63;
  const int wave = tid >> 6;
  const int quad = lane >> 4;
  const int l16  = lane & 15;
  const int wr   = wave >> 1;   // 0..3  row group (32 rows)
  const int wc   = wave & 1;    // 0..1  col half (64 cols)
  const int b    = blockIdx.x;
  const float* xb = x + (size_t)b * (NNODE * HDIM);

  const int r0 = wr * 32 + l16;
  const int r1 = r0 + 16;
  const int m0 = (r0 < NNODE) ? r0 : 0;   // clamp garbage rows (outputs discarded)
  const int m1 = (r1 < NNODE) ? r1 : 0;

  // per-thread B-fragment base: row = wc*64 + ct*16 + l16, col = kq*32 + quad*8
  // -> addr = wbase + ct*16*HDIM + kq*32; ct/kq offsets are compile-time imms.
  const int woff = (wc * 64 + l16) * HDIM + quad * 8;

  // One GEMM phase: acc[rt][ct] += A(rows ra0/ra1 of abuf) @ W. B-frags streamed
  // from global (L2-hot) with immediate offsets — minimal register footprint.
  auto gemm = [&](const short* __restrict__ w, const short* __restrict__ abuf,
                  int ra0, int ra1, f32x4 (&acc)[2][4]) {
    const short* wb = w + woff;
#pragma unroll
    for (int kq = 0; kq < 4; ++kq) {
      const int ko = kq * 32 + quad * 8;
      s16x8 a0 = *(const s16x8*)&abuf[sidx(ra0, ko)];
      s16x8 a1 = *(const s16x8*)&abuf[sidx(ra1, ko)];
#pragma unroll
      for (int ct = 0; ct < 4; ++ct) {
        s16x8 bw = *(const s16x8*)&wb[ct * 16 * HDIM + kq * 32];
        acc[0][ct] = __builtin_amdgcn_mfma_f32_16x16x32_bf16(a0, bw, acc[0][ct], 0, 0, 0);
        acc[1][ct] = __builtin_amdgcn_mfma_f32_16x16x32_bf16(a1, bw, acc[1][ct], 0, 0, 0);
      }
    }
  };

  // ---- staging ----
  for (int G = tid; G < NNODE * 16; G += NT) {
    int r = G >> 4, g = G & 15;
    const float4* p = (const float4*)(xb + r * HDIM + g * 8);
    float4 v0 = p[0], v1 = p[1];
    s16x8 h;
    h[0] = f2bf(v0.x); h[1] = f2bf(v0.y); h[2] = f2bf(v0.z); h[3] = f2bf(v0.w);
    h[4] = f2bf(v1.x); h[5] = f2bf(v1.y); h[6] = f2bf(v1.z); h[7] = f2bf(v1.w);
    *(s16x8*)&bufX[sidx(r, g * 8)] = h;
  }
  if (tid < 384) {
    int s = (tid < NEDGE) ? src_idx[tid] : 0;
    float e = (tid < NEDGE) ? edge_dir[tid] : 0.f;
    int d = (int)(e * 3.0f + 0.5f);            // dir code 0..3
    ep[tid] = (short)(s | (d << 7));
    if (tid < NEDGE) edv[d] = e;               // benign same-value race
  }
  if (tid < NNODE) ((int4*)inls)[tid] = ((const int4*)inl_g)[tid];
  if (tid < HDIM) {
    bvs[tid]  = bv_g[tid];
    bu1s[tid] = b_upd1[tid];
    bu2s[tid] = b_upd2[tid];
    gms[tid]  = gamma[tid];
    bts[tid]  = beta[tid];
  }
  __syncthreads();

  // ---- P1: t = x @ W1 -> bufT ----
  {
    f32x4 acc[2][4] = {};
    gemm(wt, bufX, m0, m1, acc);
#pragma unroll
    for (int rt = 0; rt < 2; ++rt)
#pragma unroll
      for (int i = 0; i < 4; ++i) {
        const int row = wr * 32 + rt * 16 + quad * 4 + i;
        if (row < NNODE) {   // MUST guard: bufT is only 100 rows
#pragma unroll
          for (int ct = 0; ct < 4; ++ct) {
            const int col = wc * 64 + ct * 16 + l16;
            bufT[sidx(row, col)] = f2bf(acc[rt][ct][i]);
          }
        }
      }
  }
  __syncthreads();

  // ---- P2: magg[v] = sum_{e into v} relu(t[src[e]] + b1 + ed[e]*w1L) -> bufM ----
  {
    const int ko = (tid & 15) * 8;   // constant across this thread's iterations
    const float4 ba = *(const float4*)&b_msg1[ko];
    const float4 bb = *(const float4*)&b_msg1[ko + 4];
    const float4 wa = *(const float4*)&w_msg1[HDIM * HDIM + ko];
    const float4 wb = *(const float4*)&w_msg1[HDIM * HDIM + ko + 4];
    for (int G = tid; G < NNODE * 16; G += NT) {
      const int v = G >> 4;
      const int4 il = ((const int4*)inls)[v];
      float s[8] = {0, 0, 0, 0, 0, 0, 0, 0};
      const int es[4] = {il.x, il.y, il.z, il.w};
#pragma unroll
      for (int j = 0; j < 4; ++j) {
        if (es[j] >= 0) {
          const int pk = ep[es[j]];
          const float ed = edv[pk >> 7];
          s16x8 t8 = *(const s16x8*)&bufT[sidx(pk & 127, ko)];
          float u;
          u = bf2f(t8[0]) + ba.x + ed * wa.x; s[0] += u > 0.f ? u : 0.f;
          u = bf2f(t8[1]) + ba.y + ed * wa.y; s[1] += u > 0.f ? u : 0.f;
          u = bf2f(t8[2]) + ba.z + ed * wa.z; s[2] += u > 0.f ? u : 0.f;
          u = bf2f(t8[3]) + ba.w + ed * wa.w; s[3] += u > 0.f ? u : 0.f;
          u = bf2f(t8[4]) + bb.x + ed * wb.x; s[4] += u > 0.f ? u : 0.f;
          u = bf2f(t8[5]) + bb.y + ed * wb.y; s[5] += u > 0.f ? u : 0.f;
          u = bf2f(t8[6]) + bb.z + ed * wb.z; s[6] += u > 0.f ? u : 0.f;
          u = bf2f(t8[7]) + bb.w + ed * wb.w; s[7] += u > 0.f ? u : 0.f;
        }
      }
      s16x8 o;
#pragma unroll
      for (int t = 0; t < 8; ++t) o[t] = f2bf(s[t]);
      *(s16x8*)&bufM[sidx(v, ko)] = o;
    }
  }
  __syncthreads();

  // ---- B1: u1 = relu(magg @ Wc + x @ Wu1a + bu1 + cnt*bv) -> bufT ----
  {
    f32x4 acc[2][4] = {};
    gemm(wt + 16384,     bufM, m0, m1, acc);   // magg half
    gemm(wt + 2 * 16384, bufX, m0, m1, acc);   // x half (bufX still live)
#pragma unroll
    for (int rt = 0; rt < 2; ++rt)
#pragma unroll
      for (int i = 0; i < 4; ++i) {
        const int row = wr * 32 + rt * 16 + quad * 4 + i;
        if (row < NNODE) {
          const int4 il = ((const int4*)inls)[row];
          const float cn = (float)((il.x >= 0) + (il.y >= 0) + (il.z >= 0) + (il.w >= 0));
#pragma unroll
          for (int ct = 0; ct < 4; ++ct) {
            const int col = wc * 64 + ct * 16 + l16;
            float v = acc[rt][ct][i] + bu1s[col] + cn * bvs[col];
            bufT[sidx(row, col)] = f2bf(v > 0.f ? v : 0.f);
          }
        }
      }
  }
  __syncthreads();

  // ---- B2: h = u1 @ Wu2 + bu2 + x; LN stats; h -> hbuf; coalesced LN store ----
  {
    f32x4 acc[2][4] = {};
    gemm(wt + 3 * 16384, bufT, m0, m1, acc);
    // hbuf overlays bufX+bufM (dead since barrier 4); disjoint from bufT reads -> no
    // extra barrier needed before these writes.
#pragma unroll
    for (int rt = 0; rt < 2; ++rt)
#pragma unroll
      for (int i = 0; i < 4; ++i) {
        const int row = wr * 32 + rt * 16 + quad * 4 + i;
        if (row < NNODE) {
          float s1 = 0.f, s2 = 0.f;
#pragma unroll
          for (int ct = 0; ct < 4; ++ct) {
            const int col = wc * 64 + ct * 16 + l16;
            const float h = acc[rt][ct][i] + bu2s[col] + xb[row * HDIM + col];
            hbuf[hidx(row, col)] = h;
            s1 += h; s2 += h * h;
          }
          // reduce this row's 64-col partials across the 16 lanes holding it
#pragma unroll
          for (int off = 8; off > 0; off >>= 1) {
            s1 += __shfl_xor(s1, off, 64);
            s2 += __shfl_xor(s2, off, 64);
          }
          if (l16 == 0) { lnb[row * 4 + wc * 2] = s1; lnb[row * 4 + wc * 2 + 1] = s2; }
        }
      }
    __syncthreads();
    // final: LN-apply + fully coalesced float4 stores (512B contiguous per row)
    for (int G = tid; G < NNODE * 32; G += NT) {
      const int row = G >> 5;
      const int c = (G & 31) * 4;
      const float4 h = *(const float4*)&hbuf[hidx(row, c)];
      const float s1 = lnb[row * 4] + lnb[row * 4 + 2];
      const float s2 = lnb[row * 4 + 1] + lnb[row * 4 + 3];
      const float mu  = s1 * (1.0f / HDIM);
      const float var = s2 * (1.0f / HDIM) - mu * mu;
      const float rs  = rsqrtf(var + 1e-5f);
      const float4 g  = *(const float4*)&gms[c];
      const float4 bt = *(const float4*)&bts[c];
      float4 o;
      o.x = (h.x - mu) * rs * g.x + bt.x;
      o.y = (h.y - mu) * rs * g.y + bt.y;
      o.z = (h.z - mu) * rs * g.z + bt.z;
      o.w = (h.w - mu) * rs * g.w + bt.w;
      *(float4*)&out[((size_t)b * NNODE + row) * HDIM + c] = o;
    }
  }
}

extern "C" void kernel_launch(void* const* d_in, const int* in_sizes, int n_in,
                              void* d_out, int out_size, void* d_ws, size_t ws_size,
                              hipStream_t stream) {
  const float* x      = (const float*)d_in[0];
  const int*   src    = (const int*)  d_in[1];
  const int*   dst    = (const int*)  d_in[2];
  const float* ed     = (const float*)d_in[3];
  const float* w_msg1 = (const float*)d_in[4];
  const float* b_msg1 = (const float*)d_in[5];
  const float* w_msg2 = (const float*)d_in[6];
  const float* b_msg2 = (const float*)d_in[7];
  const float* w_upd1 = (const float*)d_in[8];
  const float* b_upd1 = (const float*)d_in[9];
  const float* w_upd2 = (const float*)d_in[10];
  const float* b_upd2 = (const float*)d_in[11];
  const float* gamma  = (const float*)d_in[12];
  const float* beta   = (const float*)d_in[13];
  float* out = (float*)d_out;

  short* wt  = (short*)d_ws;                      // 4 * 32768 B (W1, Wc, Wu1a, Wu2)
  float* bv  = (float*)((char*)d_ws + 131072);    // 512 B
  int*   inl = (int*)((char*)d_ws + 131584);      // 100 * int4

  prep_all<<<129, NT, 0, stream>>>(w_msg1, w_msg2, w_upd1, w_upd2, b_msg2,
                                   dst, wt, bv, inl);

  const int Bsz = in_sizes[0] / (NNODE * HDIM);   // 2048
  mpnn_main<<<Bsz, NT, 0, stream>>>(x, src, ed, w_msg1, b_msg1,
                                    b_upd1, b_upd2, gamma, beta, wt, bv, inl, out);
}